// Round 11
// baseline (273.850 us; speedup 1.0000x reference)
//
#include <hip/hip_runtime.h>

#define N_NODES 25000
#define N_EDGES 400000
#define IN_CH 1024
#define FC 128
#define ADD_CH 20
#define XCH 148   // FC + ADD
#define MID 37
#define OUT_CH 3
#define MAXDEG 64
#define CSTRIDE 16   // cursor padded to one counter per 64B line

typedef short bf16x8 __attribute__((ext_vector_type(8)));
typedef float f32x4 __attribute__((ext_vector_type(4)));
typedef unsigned int u32x4 __attribute__((ext_vector_type(4)));

__device__ __forceinline__ float bflo(unsigned int v) {
    return __builtin_bit_cast(float, v << 16);
}
__device__ __forceinline__ float bfhi(unsigned int v) {
    return __builtin_bit_cast(float, v & 0xffff0000u);
}
// pack 2 f32 -> 2 bf16 (RNE), single VALU op
__device__ __forceinline__ unsigned int cvtpk(float a, float b) {
    unsigned int r;
    asm("v_cvt_pk_bf16_f32 %0, %1, %2" : "=v"(r) : "v"(a), "v"(b));
    return r;
}

// async 16B global->LDS DMA (counts in vmcnt)
__device__ __forceinline__ void gload16(const void* g, void* l) {
    __builtin_amdgcn_global_load_lds(
        (const __attribute__((address_space(1))) unsigned int*)g,
        (__attribute__((address_space(3))) unsigned int*)l,
        16, 0, 0);
}

// ---------------- prep: W swizzle + cursor zero (one dispatch) --------------
// Wpk layout: [kt(32)][chgrp(16)][lane(64)] x 16B; unit (kt,chgrp) lane (q,l15)
// holds W[chgrp*16+l15][kt*32+q*8 .. +8] as bf16x8. 512 KB, L2-resident.
#define WSWZ_B 16
#define ZERO_B 49   // 49*512 >= 25000

__global__ __launch_bounds__(512) void prep(const float* __restrict__ Wl,
                                            const float* __restrict__ Wr,
                                            ushort* __restrict__ Wpk,
                                            int* __restrict__ cursor) {
    int b = blockIdx.x, t = threadIdx.x;
    if (b < WSWZ_B) {
        int w = t >> 6, lane = t & 63, l15 = lane & 15, q8 = (lane >> 4) * 8;
        int ch = b * 16 + l15;
        const float* src = (ch < FC) ? (Wl + (size_t)ch * IN_CH)
                                     : (Wr + (size_t)(ch - FC) * IN_CH);
        #pragma unroll
        for (int j = 0; j < 4; ++j) {
            int kt = w * 4 + j;
            float4 lo = *(const float4*)(src + kt * 32 + q8);
            float4 hi = *(const float4*)(src + kt * 32 + q8 + 4);
            uint4 pk;
            pk.x = cvtpk(lo.x, lo.y); pk.y = cvtpk(lo.z, lo.w);
            pk.z = cvtpk(hi.x, hi.y); pk.w = cvtpk(hi.z, hi.w);
            ((uint4*)Wpk)[((size_t)kt * 16 + b) * 64 + lane] = pk;
        }
    } else {
        int i = (b - WSWZ_B) * 512 + t;
        if (i < N_NODES) {
            uint4 z = {0, 0, 0, 0};
            uint4* dst = (uint4*)(cursor + (size_t)i * CSTRIDE);
            dst[0] = z; dst[1] = z; dst[2] = z; dst[3] = z;
        }
    }
}

// ---------------- hetero: high-occupancy hybrid GEMM + ILP build ------------
// 11-round synthesis: per-wave pipelining was never the binder -- OCCUPANCY
// was (391 blocks = 1.5/CU = 12 waves/CU in every "good" config; R5 proved
// 782 blocks -> 56% occ but was poisoned by __syncthreads convoy + W-in-LDS).
// This round: R5's grid x R10's mechanics.
//   * M=32 tile -> 782 gemm blocks (~3/CU); target 24 waves/CU (75%).
//   * K-chunk = 64 floats -> 16 chunks (half the barriers); A-chunk 8 KB =
//     512 slots -> ALL 512 threads stage 1 gload16 -> vmcnt uniform.
//   * A double-buffered in 16 KB LDS (shared by 8 waves); W direct L2->regs
//     via asm-pinned banks (R10: compiler cannot collapse).
//   * 5 vmem ops/chunk/thread (1 A + 4 W); steady wait vmcnt(5) = depth-2.
//     24 waves/CU interleave covers the latency the shallow queue exposes.
//   Wave w: ch {2w,2w+1 chgrps} x 32 nodes -> acc[2][2]; 8 MFMA/chunk.
//   LDS slot (h,g,hq,lane): feat[m0+g*16+l15][c*64 + h*32 + q*8 + hq*4 ..+4].
// Build rides along unchanged (4-edge ILP chains).
#define GEMM_B 782    // ceil(25000/32)
#define BUILD_B 196   // ceil(400000/2048)

__global__ __launch_bounds__(512, 6) void gemm_build(const float* __restrict__ A,
                                                     const ushort* __restrict__ Wpk,
                                                     ushort* __restrict__ Py,
                                                     ushort* __restrict__ Pz,
                                                     const int* __restrict__ edges,
                                                     int* __restrict__ cursor,
                                                     int* __restrict__ col) {
    __shared__ uint4 LDS[2][512];    // A only: 2 bufs x 8 KB = 16 KB
    int b = blockIdx.x, t = threadIdx.x;
    if (b >= GEMM_B) {
        int base = (b - GEMM_B) * 2048 + t;
        int src[4], dst[4], pos[4];
        #pragma unroll
        for (int k = 0; k < 4; ++k) {
            int e = base + k * 512;
            bool v = (e < N_EDGES);
            dst[k] = v ? edges[N_EDGES + e] : 0;
            src[k] = v ? edges[e] : 0;
        }
        #pragma unroll
        for (int k = 0; k < 4; ++k) {
            int e = base + k * 512;
            if (e < N_EDGES)
                pos[k] = atomicAdd(&cursor[(size_t)dst[k] * CSTRIDE], 1);
        }
        #pragma unroll
        for (int k = 0; k < 4; ++k) {
            int e = base + k * 512;
            if (e < N_EDGES && pos[k] < MAXDEG)
                col[dst[k] * MAXDEG + pos[k]] = src[k];
        }
        return;
    }
    int m0 = b * 32;
    int w = t >> 6, lane = t & 63;
    int l15 = lane & 15, q = lane >> 4;
    int tb_ = t & ~63;                // wave-uniform LDS slot base

    // A staging source: thread t stages slot t = (h=t>>8, g, hq, lane)
    int sh = t >> 8, sg = (t >> 7) & 1, shq = (t >> 6) & 1;
    int nodeA = m0 + sg * 16 + l15;
    if (nodeA >= N_NODES) nodeA = N_NODES - 1;
    const float* Asrc = A + (size_t)nodeA * IN_CH + sh * 32 + ((t >> 4) & 3) * 8 + shq * 4;

    // W byte offset of (kt=2c, chgrp=2w) frag: c*32768 + w*2048 + lane*16
    unsigned voff0 = (unsigned)(w * 2048 + lane * 16);

    f32x4 acc[2][2] = {};
    u32x4 wa0, wa1, wa2, wa3, wb0, wb1, wb2, wb3;  // banks A/B: [h][chgrp-idx]

    #define ISSUE_W(R0, R1, R2, R3, vo, vo2)                                      \
        asm volatile("global_load_dwordx4 %0, %4, %5\n\t"                         \
                     "global_load_dwordx4 %1, %4, %5 offset:1024\n\t"             \
                     "global_load_dwordx4 %2, %6, %5\n\t"                         \
                     "global_load_dwordx4 %3, %6, %5 offset:1024"                 \
                     : "=&v"(R0), "=&v"(R1), "=&v"(R2), "=&v"(R3)                 \
                     : "v"(vo), "s"(Wpk), "v"(vo2) : "memory");

    // prologue: chunk 0 -> (LDS0, bankA); 5 ops in flight
    gload16(Asrc, &LDS[0][tb_]);
    { unsigned vo = voff0, vo2 = voff0 + 16384u; ISSUE_W(wa0, wa1, wa2, wa3, vo, vo2) }

    #define COMPUTE(R0, R1, R2, R3, cb)                                           \
    {                                                                             \
        _Pragma("unroll")                                                         \
        for (int h = 0; h < 2; ++h) {                                             \
            bf16x8 wf0 = __builtin_bit_cast(bf16x8, h ? R2 : R0);                 \
            bf16x8 wf1 = __builtin_bit_cast(bf16x8, h ? R3 : R1);                 \
            _Pragma("unroll")                                                     \
            for (int g = 0; g < 2; ++g) {                                         \
                f32x4 lo = *(const f32x4*)&LDS[cb][(h * 4 + g * 2 + 0) * 64 + lane]; \
                f32x4 hi = *(const f32x4*)&LDS[cb][(h * 4 + g * 2 + 1) * 64 + lane]; \
                uint4 pk_;                                                        \
                pk_.x = cvtpk(lo[0], lo[1]); pk_.y = cvtpk(lo[2], lo[3]);         \
                pk_.z = cvtpk(hi[0], hi[1]); pk_.w = cvtpk(hi[2], hi[3]);         \
                bf16x8 af = __builtin_bit_cast(bf16x8, pk_);                      \
                acc[0][g] = __builtin_amdgcn_mfma_f32_16x16x32_bf16(wf0, af, acc[0][g], 0, 0, 0); \
                acc[1][g] = __builtin_amdgcn_mfma_f32_16x16x32_bf16(wf1, af, acc[1][g], 0, 0, 0); \
            }                                                                     \
        }                                                                         \
    }

    #define STEP(c, S0, S1, S2, S3, C0, C1, C2, C3, SBUF, CBUF)                   \
    {                                                                             \
        gload16(Asrc + (size_t)((c) + 1) * 64, &LDS[SBUF][tb_]);                  \
        unsigned vo = voff0 + (unsigned)((c) + 1) * 32768u;                       \
        unsigned vo2 = vo + 16384u;                                               \
        ISSUE_W(S0, S1, S2, S3, vo, vo2)                                          \
        asm volatile("s_waitcnt vmcnt(5)" ::: "memory");                          \
        __builtin_amdgcn_sched_barrier(0);                                        \
        __builtin_amdgcn_s_barrier();                                             \
        __builtin_amdgcn_sched_barrier(0);                                        \
        COMPUTE(C0, C1, C2, C3, CBUF);                                            \
        __builtin_amdgcn_s_barrier();                                             \
        __builtin_amdgcn_sched_barrier(0);                                        \
    }

    for (int cc = 0; cc < 14; cc += 2) {
        STEP(cc,     wb0, wb1, wb2, wb3, wa0, wa1, wa2, wa3, 1, 0)
        STEP(cc + 1, wa0, wa1, wa2, wa3, wb0, wb1, wb2, wb3, 0, 1)
    }
    STEP(14, wb0, wb1, wb2, wb3, wa0, wa1, wa2, wa3, 1, 0)
    // final chunk 15 (LDS1/bankB): drain fully
    asm volatile("s_waitcnt vmcnt(0)" ::: "memory");
    __builtin_amdgcn_sched_barrier(0);
    __builtin_amdgcn_s_barrier();
    __builtin_amdgcn_sched_barrier(0);
    COMPUTE(wb0, wb1, wb2, wb3, 1);
    #undef STEP
    #undef COMPUTE
    #undef ISSUE_W

    // D layout: ch = w*32 + cf*16 + q*4 + reg, node = m0 + g*16 + l15
    #pragma unroll
    for (int g = 0; g < 2; ++g) {
        int node = m0 + g * 16 + l15;
        if (node < N_NODES) {
            ushort* base = (w < 4) ? (Py + (size_t)node * FC + w * 32)
                                   : (Pz + (size_t)node * FC + (w - 4) * 32);
            #pragma unroll
            for (int cf = 0; cf < 2; ++cf) {
                f32x4 v = acc[cf][g];
                uint2 pk;
                pk.x = cvtpk(v[0], v[1]);
                pk.y = cvtpk(v[2], v[3]);
                *(uint2*)(base + cf * 16 + q * 4) = pk;
            }
        }
    }
}

// ---------------- fused gather + SAGE combine + MLP tail (8 nodes/block) ----
__global__ __launch_bounds__(512) void fused_tail(const ushort* __restrict__ Py,
                                                  const ushort* __restrict__ Pz,
                                                  const int* __restrict__ deg,
                                                  const int* __restrict__ col,
                                                  const float* __restrict__ addf,
                                                  const float* __restrict__ bl,
                                                  const float* __restrict__ W1,
                                                  const float* __restrict__ b1,
                                                  const float* __restrict__ W2,
                                                  const float* __restrict__ b2,
                                                  const float* __restrict__ gamma,
                                                  const float* __restrict__ beta,
                                                  const float* __restrict__ rmean,
                                                  const float* __restrict__ rvar,
                                                  float* __restrict__ out) {
    __shared__ float W1s[XCH][MID + 3];
    __shared__ float xbuf[8][XCH + 4];
    __shared__ float hbuf[8][MID + 3];
    int t = threadIdx.x;
    for (int idx = t; idx < MID * XCH; idx += 512) {
        int j = idx / XCH, k = idx - j * XCH;
        W1s[k][j] = W1[idx];
    }
    __syncthreads();
    int w = t >> 6, lane = t & 63;
    int n = blockIdx.x * 8 + w;
    bool valid = (n < N_NODES);
    int d = valid ? deg[(size_t)n * CSTRIDE] : 0;
    if (d > MAXDEG) d = MAXDEG;
    int g = lane >> 4, c16 = lane & 15;
    float s[8] = {0.f, 0.f, 0.f, 0.f, 0.f, 0.f, 0.f, 0.f};
    if (d > 0) {
        int cidx = col[n * MAXDEG + (lane < d ? lane : 0)];
        for (int i = 0; i < d; i += 16) {
            int e[4];
            uint4 v[4];
            #pragma unroll
            for (int j = 0; j < 4; ++j) {
                int ee = i + g + j * 4;
                e[j] = __shfl(cidx, (ee < d) ? ee : 0);
            }
            #pragma unroll
            for (int j = 0; j < 4; ++j)
                v[j] = *(const uint4*)&Py[(size_t)e[j] * FC + c16 * 8];
            #pragma unroll
            for (int j = 0; j < 4; ++j) {
                if (i + g + j * 4 < d) {
                    s[0] += bflo(v[j].x); s[1] += bfhi(v[j].x);
                    s[2] += bflo(v[j].y); s[3] += bfhi(v[j].y);
                    s[4] += bflo(v[j].z); s[5] += bfhi(v[j].z);
                    s[6] += bflo(v[j].w); s[7] += bfhi(v[j].w);
                }
            }
        }
        #pragma unroll
        for (int r = 0; r < 8; ++r) {
            s[r] += __shfl_xor(s[r], 16);
            s[r] += __shfl_xor(s[r], 32);
        }
    }
    if (valid) {
        if (lane < 16) {
            #pragma unroll
            for (int r = 0; r < 8; ++r) xbuf[w][lane * 8 + r] = s[r];
        }
        float invd = 1.0f / (float)(d > 1 ? d : 1);
        unsigned int vr = *(const unsigned int*)&Pz[(size_t)n * FC + lane * 2];
        float x0 = xbuf[w][2 * lane] * invd + bl[2 * lane] + bflo(vr);
        float x1 = xbuf[w][2 * lane + 1] * invd + bl[2 * lane + 1] + bfhi(vr);
        x0 = (x0 >= 0.f) ? x0 : 0.01f * x0;
        x1 = (x1 >= 0.f) ? x1 : 0.01f * x1;
        xbuf[w][2 * lane] = x0;
        xbuf[w][2 * lane + 1] = x1;
        if (lane < ADD_CH) xbuf[w][FC + lane] = addf[(size_t)n * ADD_CH + lane];
        if (lane < MID) {
            float h = b1[lane];
            #pragma unroll 4
            for (int k = 0; k < XCH; ++k) h += W1s[k][lane] * xbuf[w][k];
            h = fmaxf(h, 0.0f);
            h = gamma[lane] * (h - rmean[lane]) * rsqrtf(rvar[lane] + 1e-5f) + beta[lane];
            hbuf[w][lane] = h;
        }
        if (lane < OUT_CH) {
            float o = b2[lane];
            #pragma unroll
            for (int j = 0; j < MID; ++j) o += W2[lane * MID + j] * hbuf[w][j];
            out[(size_t)n * OUT_CH + lane] = o;
        }
    }
}

// ---------------- launch ----------------

extern "C" void kernel_launch(void* const* d_in, const int* in_sizes, int n_in,
                              void* d_out, int out_size, void* d_ws, size_t ws_size,
                              hipStream_t stream) {
    const float* features = (const float*)d_in[0];
    const int*   edges    = (const int*)d_in[1];
    const float* addf     = (const float*)d_in[4];
    const float* Wl       = (const float*)d_in[5];
    const float* bl       = (const float*)d_in[6];
    const float* Wr       = (const float*)d_in[7];
    const float* W1       = (const float*)d_in[8];
    const float* b1       = (const float*)d_in[9];
    const float* W2       = (const float*)d_in[10];
    const float* b2       = (const float*)d_in[11];
    const float* gamma    = (const float*)d_in[12];
    const float* beta     = (const float*)d_in[13];
    const float* rmean    = (const float*)d_in[14];
    const float* rvar     = (const float*)d_in[15];
    float* out = (float*)d_out;

    char* ws = (char*)d_ws;
    size_t off = 0;
    ushort* Py = (ushort*)(ws + off);     off += (size_t)N_NODES * FC * 2;            // 6.4 MB
    ushort* Pz = (ushort*)(ws + off);     off += (size_t)N_NODES * FC * 2;            // 6.4 MB
    ushort* Wpk = (ushort*)(ws + off);    off += (size_t)32 * 16 * 64 * 16;           // 512 KB
    int* cursor = (int*)(ws + off);       off += (size_t)N_NODES * CSTRIDE * 4;       // 1.6 MB
    int* col = (int*)(ws + off);          off += (size_t)N_NODES * MAXDEG * 4;        // 6.4 MB

    prep<<<WSWZ_B + ZERO_B, 512, 0, stream>>>(Wl, Wr, Wpk, cursor);

    gemm_build<<<GEMM_B + BUILD_B, 512, 0, stream>>>(features, Wpk, Py, Pz,
                                                     edges, cursor, col);

    fused_tail<<<(N_NODES + 7) / 8, 512, 0, stream>>>(Py, Pz, cursor, col, addf, bl,
                                                      W1, b1, W2, b2, gamma, beta,
                                                      rmean, rvar, out);
}

// Round 12
// 272.951 us; speedup vs baseline: 1.0033x; 1.0033x over previous
//
#include <hip/hip_runtime.h>

#define N_NODES 25000
#define N_EDGES 400000
#define IN_CH 1024
#define FC 128
#define ADD_CH 20
#define XCH 148   // FC + ADD
#define MID 37
#define OUT_CH 3
#define MAXDEG 64
#define CSTRIDE 16   // cursor padded to one counter per 64B line

typedef short bf16x8 __attribute__((ext_vector_type(8)));
typedef float f32x4 __attribute__((ext_vector_type(4)));

__device__ __forceinline__ float bflo(unsigned int v) {
    return __builtin_bit_cast(float, v << 16);
}
__device__ __forceinline__ float bfhi(unsigned int v) {
    return __builtin_bit_cast(float, v & 0xffff0000u);
}
// pack 2 f32 -> 2 bf16 (RNE), single VALU op
__device__ __forceinline__ unsigned int cvtpk(float a, float b) {
    unsigned int r;
    asm("v_cvt_pk_bf16_f32 %0, %1, %2" : "=v"(r) : "v"(a), "v"(b));
    return r;
}

// async 16B global->LDS DMA (counts in vmcnt)
__device__ __forceinline__ void gload16(const void* g, void* l) {
    __builtin_amdgcn_global_load_lds(
        (const __attribute__((address_space(1))) unsigned int*)g,
        (__attribute__((address_space(3))) unsigned int*)l,
        16, 0, 0);
}

// ---------------- prep: W swizzle + cursor zero (one dispatch) --------------
// Wpk layout: [kt(32)][chgrp(16)][lane(64)] x 16B -> one K-chunk (one kt) of
// all 256 channels is a CONTIGUOUS 16 KB slab for linear global_load_lds.
#define WSWZ_B 16
#define ZERO_B 49   // 49*512 >= 25000 (each thread zeroes one padded line)

__global__ __launch_bounds__(512) void prep(const float* __restrict__ Wl,
                                            const float* __restrict__ Wr,
                                            ushort* __restrict__ Wpk,
                                            int* __restrict__ cursor) {
    int b = blockIdx.x, t = threadIdx.x;
    if (b < WSWZ_B) {
        int w = t >> 6, lane = t & 63, l15 = lane & 15, q8 = (lane >> 4) * 8;
        int ch = b * 16 + l15;
        const float* src = (ch < FC) ? (Wl + (size_t)ch * IN_CH)
                                     : (Wr + (size_t)(ch - FC) * IN_CH);
        #pragma unroll
        for (int j = 0; j < 4; ++j) {
            int kt = w * 4 + j;
            float4 lo = *(const float4*)(src + kt * 32 + q8);
            float4 hi = *(const float4*)(src + kt * 32 + q8 + 4);
            uint4 pk;
            pk.x = cvtpk(lo.x, lo.y); pk.y = cvtpk(lo.z, lo.w);
            pk.z = cvtpk(hi.x, hi.y); pk.w = cvtpk(hi.z, hi.w);
            ((uint4*)Wpk)[((size_t)kt * 16 + b) * 64 + lane] = pk;
        }
    } else {
        int i = (b - WSWZ_B) * 512 + t;
        if (i < N_NODES) {
            uint4 z = {0, 0, 0, 0};
            uint4* dst = (uint4*)(cursor + (size_t)i * CSTRIDE);
            dst[0] = z; dst[1] = z; dst[2] = z; dst[3] = z;
        }
    }
}

// ---------------- hetero: depth-3 counted-vmcnt GEMM + ILP build ------------
// REVERTED VERBATIM to round-8 config (session best: 66us, total 255).
// R5/R11 falsified occupancy theory; R0-R11 bracket this dispatch 62-84us
// under every pipelining/occupancy/LDS variant -> locally converged.
#define GEMM_B 391    // ceil(25000/64)
#define BUILD_B 196   // ceil(400000/2048)

__global__ __launch_bounds__(512, 4) void gemm_build(const float* __restrict__ A,
                                                     const ushort* __restrict__ Wpk,
                                                     ushort* __restrict__ Py,
                                                     ushort* __restrict__ Pz,
                                                     const int* __restrict__ edges,
                                                     int* __restrict__ cursor,
                                                     int* __restrict__ col) {
    __shared__ uint4 LDS[3][1536];   // [buf][ 0..1023 = W | 1024..1535 = A ]  72 KB
    int b = blockIdx.x, t = threadIdx.x;
    if (b >= GEMM_B) {
        int base = (b - GEMM_B) * 2048 + t;
        int src[4], dst[4], pos[4];
        #pragma unroll
        for (int k = 0; k < 4; ++k) {
            int e = base + k * 512;
            bool v = (e < N_EDGES);
            dst[k] = v ? edges[N_EDGES + e] : 0;
            src[k] = v ? edges[e] : 0;
        }
        #pragma unroll
        for (int k = 0; k < 4; ++k) {
            int e = base + k * 512;
            if (e < N_EDGES)
                pos[k] = atomicAdd(&cursor[(size_t)dst[k] * CSTRIDE], 1);
        }
        #pragma unroll
        for (int k = 0; k < 4; ++k) {
            int e = base + k * 512;
            if (e < N_EDGES && pos[k] < MAXDEG)
                col[dst[k] * MAXDEG + pos[k]] = src[k];
        }
        return;
    }
    int m0 = b * 64;

    int ga = t >> 7, hq = (t >> 6) & 1, la = t & 63;
    int nodeA = m0 + ga * 16 + (la & 15);
    if (nodeA >= N_NODES) nodeA = N_NODES - 1;
    const float* Asrc = A + (size_t)nodeA * IN_CH + (la >> 4) * 8 + hq * 4;
    const uint4* Wg = (const uint4*)Wpk;
    int tb = t & ~63;                 // wave-uniform LDS slot base

    int w = t >> 6, lane = t & 63;
    int wm = w >> 2, wn = w & 3;
    int l15 = lane & 15, q = lane >> 4;

    f32x4 acc[4][2] = {};

    // prologue: stage chunk 0 -> buf0, chunk 1 -> buf1 (6 loads in flight)
    gload16(Wg + t,        &LDS[0][tb]);
    gload16(Wg + 512 + t,  &LDS[0][512 + tb]);
    gload16(Asrc,          &LDS[0][1024 + tb]);
    gload16(Wg + 1024 + t,       &LDS[1][tb]);
    gload16(Wg + 1024 + 512 + t, &LDS[1][512 + tb]);
    gload16(Asrc + 32,           &LDS[1][1024 + tb]);

    #define COMPUTE(bc)                                                           \
    {                                                                             \
        bf16x8 wf[4];                                                             \
        _Pragma("unroll")                                                         \
        for (int i = 0; i < 4; ++i)                                               \
            wf[i] = *(const bf16x8*)&LDS[bc][(wn * 4 + i) * 64 + lane];           \
        bf16x8 af[2];                                                             \
        _Pragma("unroll")                                                         \
        for (int g2 = 0; g2 < 2; ++g2) {                                          \
            f32x4 lo = *(const f32x4*)&LDS[bc][1024 + ((wm * 2 + g2) * 2 + 0) * 64 + lane]; \
            f32x4 hi = *(const f32x4*)&LDS[bc][1024 + ((wm * 2 + g2) * 2 + 1) * 64 + lane]; \
            uint4 pk;                                                             \
            pk.x = cvtpk(lo[0], lo[1]); pk.y = cvtpk(lo[2], lo[3]);               \
            pk.z = cvtpk(hi[0], hi[1]); pk.w = cvtpk(hi[2], hi[3]);               \
            af[g2] = __builtin_bit_cast(bf16x8, pk);                              \
        }                                                                         \
        _Pragma("unroll")                                                         \
        for (int i = 0; i < 4; ++i)                                               \
            _Pragma("unroll")                                                     \
            for (int g2 = 0; g2 < 2; ++g2)                                        \
                acc[i][g2] = __builtin_amdgcn_mfma_f32_16x16x32_bf16(wf[i], af[g2], acc[i][g2], 0, 0, 0); \
    }

    int bc = 0, bs = 2;               // compute buf, stage buf
    for (int c = 0; c < 30; ++c) {
        const uint4* ws = Wg + (size_t)(c + 2) * 1024;
        gload16(ws + t,       &LDS[bs][tb]);
        gload16(ws + 512 + t, &LDS[bs][512 + tb]);
        gload16(Asrc + (size_t)(c + 2) * 32, &LDS[bs][1024 + tb]);
        asm volatile("s_waitcnt vmcnt(6)" ::: "memory");
        __builtin_amdgcn_sched_barrier(0);
        __builtin_amdgcn_s_barrier();
        __builtin_amdgcn_sched_barrier(0);
        COMPUTE(bc);
        __builtin_amdgcn_s_barrier();
        __builtin_amdgcn_sched_barrier(0);
        bc = (bc == 2) ? 0 : bc + 1;
        bs = (bs == 2) ? 0 : bs + 1;
    }
    asm volatile("s_waitcnt vmcnt(3)" ::: "memory");
    __builtin_amdgcn_sched_barrier(0);
    __builtin_amdgcn_s_barrier();
    __builtin_amdgcn_sched_barrier(0);
    COMPUTE(bc);
    bc = (bc == 2) ? 0 : bc + 1;
    asm volatile("s_waitcnt vmcnt(0)" ::: "memory");
    __builtin_amdgcn_sched_barrier(0);
    __builtin_amdgcn_s_barrier();
    __builtin_amdgcn_sched_barrier(0);
    COMPUTE(bc);
    #undef COMPUTE

    #pragma unroll
    for (int g2 = 0; g2 < 2; ++g2) {
        int node = m0 + wm * 32 + g2 * 16 + l15;
        if (node < N_NODES) {
            ushort* base = (wn < 2) ? (Py + (size_t)node * FC + (wn & 1) * 64 + q * 4)
                                    : (Pz + (size_t)node * FC + (wn & 1) * 64 + q * 4);
            #pragma unroll
            for (int i = 0; i < 4; ++i) {
                f32x4 v = acc[i][g2];
                uint2 pk;
                pk.x = cvtpk(v[0], v[1]);
                pk.y = cvtpk(v[2], v[3]);
                *(uint2*)(base + i * 16) = pk;
            }
        }
    }
}

// ---------------- fused gather + SAGE combine + MLP tail (32 nodes/block) ---
// ROUND-12 change: 32 nodes/block (782 blocks, wave processes 4 nodes
// sequentially). W1s re-staging drops 3125->782 blocks (68->17 MB of
// redundant W1 reads) and per-block fixed overhead /4. LDS ~48 KB ->
// 3 blocks/CU = 24 waves/CU; gather latency stays TLP-hidden.
__global__ __launch_bounds__(512) void fused_tail(const ushort* __restrict__ Py,
                                                  const ushort* __restrict__ Pz,
                                                  const int* __restrict__ deg,
                                                  const int* __restrict__ col,
                                                  const float* __restrict__ addf,
                                                  const float* __restrict__ bl,
                                                  const float* __restrict__ W1,
                                                  const float* __restrict__ b1,
                                                  const float* __restrict__ W2,
                                                  const float* __restrict__ b2,
                                                  const float* __restrict__ gamma,
                                                  const float* __restrict__ beta,
                                                  const float* __restrict__ rmean,
                                                  const float* __restrict__ rvar,
                                                  float* __restrict__ out) {
    __shared__ float W1s[XCH][MID + 3];
    __shared__ float xbuf[32][XCH + 4];
    __shared__ float hbuf[32][MID + 3];
    int t = threadIdx.x;
    for (int idx = t; idx < MID * XCH; idx += 512) {
        int j = idx / XCH, k = idx - j * XCH;
        W1s[k][j] = W1[idx];
    }
    __syncthreads();
    int w = t >> 6, lane = t & 63;
    int g = lane >> 4, c16 = lane & 15;
    #pragma unroll 1
    for (int i4 = 0; i4 < 4; ++i4) {
        int sidx = w * 4 + i4;
        int n = blockIdx.x * 32 + sidx;
        bool valid = (n < N_NODES);
        int d = valid ? deg[(size_t)n * CSTRIDE] : 0;
        if (d > MAXDEG) d = MAXDEG;
        float s[8] = {0.f, 0.f, 0.f, 0.f, 0.f, 0.f, 0.f, 0.f};
        if (d > 0) {
            int cidx = col[n * MAXDEG + (lane < d ? lane : 0)];
            for (int i = 0; i < d; i += 16) {
                int e[4];
                uint4 v[4];
                #pragma unroll
                for (int j = 0; j < 4; ++j) {
                    int ee = i + g + j * 4;
                    e[j] = __shfl(cidx, (ee < d) ? ee : 0);
                }
                #pragma unroll
                for (int j = 0; j < 4; ++j)
                    v[j] = *(const uint4*)&Py[(size_t)e[j] * FC + c16 * 8];
                #pragma unroll
                for (int j = 0; j < 4; ++j) {
                    if (i + g + j * 4 < d) {
                        s[0] += bflo(v[j].x); s[1] += bfhi(v[j].x);
                        s[2] += bflo(v[j].y); s[3] += bfhi(v[j].y);
                        s[4] += bflo(v[j].z); s[5] += bfhi(v[j].z);
                        s[6] += bflo(v[j].w); s[7] += bfhi(v[j].w);
                    }
                }
            }
            #pragma unroll
            for (int r = 0; r < 8; ++r) {
                s[r] += __shfl_xor(s[r], 16);
                s[r] += __shfl_xor(s[r], 32);
            }
        }
        if (valid) {
            if (lane < 16) {
                #pragma unroll
                for (int r = 0; r < 8; ++r) xbuf[sidx][lane * 8 + r] = s[r];
            }
            float invd = 1.0f / (float)(d > 1 ? d : 1);
            unsigned int vr = *(const unsigned int*)&Pz[(size_t)n * FC + lane * 2];
            float x0 = xbuf[sidx][2 * lane] * invd + bl[2 * lane] + bflo(vr);
            float x1 = xbuf[sidx][2 * lane + 1] * invd + bl[2 * lane + 1] + bfhi(vr);
            x0 = (x0 >= 0.f) ? x0 : 0.01f * x0;
            x1 = (x1 >= 0.f) ? x1 : 0.01f * x1;
            xbuf[sidx][2 * lane] = x0;
            xbuf[sidx][2 * lane + 1] = x1;
            if (lane < ADD_CH) xbuf[sidx][FC + lane] = addf[(size_t)n * ADD_CH + lane];
            if (lane < MID) {
                float h = b1[lane];
                #pragma unroll 4
                for (int k = 0; k < XCH; ++k) h += W1s[k][lane] * xbuf[sidx][k];
                h = fmaxf(h, 0.0f);
                h = gamma[lane] * (h - rmean[lane]) * rsqrtf(rvar[lane] + 1e-5f) + beta[lane];
                hbuf[sidx][lane] = h;
            }
            if (lane < OUT_CH) {
                float o = b2[lane];
                #pragma unroll
                for (int j = 0; j < MID; ++j) o += W2[lane * MID + j] * hbuf[sidx][j];
                out[(size_t)n * OUT_CH + lane] = o;
            }
        }
    }
}

// ---------------- launch ----------------

extern "C" void kernel_launch(void* const* d_in, const int* in_sizes, int n_in,
                              void* d_out, int out_size, void* d_ws, size_t ws_size,
                              hipStream_t stream) {
    const float* features = (const float*)d_in[0];
    const int*   edges    = (const int*)d_in[1];
    const float* addf     = (const float*)d_in[4];
    const float* Wl       = (const float*)d_in[5];
    const float* bl       = (const float*)d_in[6];
    const float* Wr       = (const float*)d_in[7];
    const float* W1       = (const float*)d_in[8];
    const float* b1       = (const float*)d_in[9];
    const float* W2       = (const float*)d_in[10];
    const float* b2       = (const float*)d_in[11];
    const float* gamma    = (const float*)d_in[12];
    const float* beta     = (const float*)d_in[13];
    const float* rmean    = (const float*)d_in[14];
    const float* rvar     = (const float*)d_in[15];
    float* out = (float*)d_out;

    char* ws = (char*)d_ws;
    size_t off = 0;
    ushort* Py = (ushort*)(ws + off);     off += (size_t)N_NODES * FC * 2;            // 6.4 MB
    ushort* Pz = (ushort*)(ws + off);     off += (size_t)N_NODES * FC * 2;            // 6.4 MB
    ushort* Wpk = (ushort*)(ws + off);    off += (size_t)32 * 16 * 64 * 16;           // 512 KB
    int* cursor = (int*)(ws + off);       off += (size_t)N_NODES * CSTRIDE * 4;       // 1.6 MB
    int* col = (int*)(ws + off);          off += (size_t)N_NODES * MAXDEG * 4;        // 6.4 MB

    prep<<<WSWZ_B + ZERO_B, 512, 0, stream>>>(Wl, Wr, Wpk, cursor);

    gemm_build<<<GEMM_B + BUILD_B, 512, 0, stream>>>(features, Wpk, Py, Pz,
                                                     edges, cursor, col);

    fused_tail<<<(N_NODES + 31) / 32, 512, 0, stream>>>(Py, Pz, cursor, col, addf, bl,
                                                        W1, b1, W2, b2, gamma, beta,
                                                        rmean, rvar, out);
}

// Round 13
// 261.823 us; speedup vs baseline: 1.0459x; 1.0425x over previous
//
#include <hip/hip_runtime.h>

#define N_NODES 25000
#define N_EDGES 400000
#define IN_CH 1024
#define FC 128
#define ADD_CH 20
#define XCH 148   // FC + ADD
#define MID 37
#define OUT_CH 3
#define MAXDEG 64
#define CSTRIDE 16   // cursor padded to one counter per 64B line

typedef short bf16x8 __attribute__((ext_vector_type(8)));
typedef float f32x4 __attribute__((ext_vector_type(4)));

__device__ __forceinline__ float bflo(unsigned int v) {
    return __builtin_bit_cast(float, v << 16);
}
__device__ __forceinline__ float bfhi(unsigned int v) {
    return __builtin_bit_cast(float, v & 0xffff0000u);
}
// pack 2 f32 -> 2 bf16 (RNE), single VALU op
__device__ __forceinline__ unsigned int cvtpk(float a, float b) {
    unsigned int r;
    asm("v_cvt_pk_bf16_f32 %0, %1, %2" : "=v"(r) : "v"(a), "v"(b));
    return r;
}

// async 16B global->LDS DMA (counts in vmcnt)
__device__ __forceinline__ void gload16(const void* g, void* l) {
    __builtin_amdgcn_global_load_lds(
        (const __attribute__((address_space(1))) unsigned int*)g,
        (__attribute__((address_space(3))) unsigned int*)l,
        16, 0, 0);
}

// ---------------- prep: W swizzle + cursor zero (one dispatch) --------------
#define WSWZ_B 16
#define ZERO_B 49   // 49*512 >= 25000 (each thread zeroes one padded line)

__global__ __launch_bounds__(512) void prep(const float* __restrict__ Wl,
                                            const float* __restrict__ Wr,
                                            ushort* __restrict__ Wpk,
                                            int* __restrict__ cursor) {
    int b = blockIdx.x, t = threadIdx.x;
    if (b < WSWZ_B) {
        int w = t >> 6, lane = t & 63, l15 = lane & 15, q8 = (lane >> 4) * 8;
        int ch = b * 16 + l15;
        const float* src = (ch < FC) ? (Wl + (size_t)ch * IN_CH)
                                     : (Wr + (size_t)(ch - FC) * IN_CH);
        #pragma unroll
        for (int j = 0; j < 4; ++j) {
            int kt = w * 4 + j;
            float4 lo = *(const float4*)(src + kt * 32 + q8);
            float4 hi = *(const float4*)(src + kt * 32 + q8 + 4);
            uint4 pk;
            pk.x = cvtpk(lo.x, lo.y); pk.y = cvtpk(lo.z, lo.w);
            pk.z = cvtpk(hi.x, hi.y); pk.w = cvtpk(hi.z, hi.w);
            ((uint4*)Wpk)[((size_t)kt * 16 + b) * 64 + lane] = pk;
        }
    } else {
        int i = (b - WSWZ_B) * 512 + t;
        if (i < N_NODES) {
            uint4 z = {0, 0, 0, 0};
            uint4* dst = (uint4*)(cursor + (size_t)i * CSTRIDE);
            dst[0] = z; dst[1] = z; dst[2] = z; dst[3] = z;
        }
    }
}

// ---------------- hetero: depth-3 counted-vmcnt GEMM + ILP build ------------
// UNCHANGED from round-8/12 (session-best config; locally converged).
#define GEMM_B 391    // ceil(25000/64)
#define BUILD_B 196   // ceil(400000/2048)

__global__ __launch_bounds__(512, 4) void gemm_build(const float* __restrict__ A,
                                                     const ushort* __restrict__ Wpk,
                                                     ushort* __restrict__ Py,
                                                     ushort* __restrict__ Pz,
                                                     const int* __restrict__ edges,
                                                     int* __restrict__ cursor,
                                                     int* __restrict__ col) {
    __shared__ uint4 LDS[3][1536];   // [buf][ 0..1023 = W | 1024..1535 = A ]  72 KB
    int b = blockIdx.x, t = threadIdx.x;
    if (b >= GEMM_B) {
        int base = (b - GEMM_B) * 2048 + t;
        int src[4], dst[4], pos[4];
        #pragma unroll
        for (int k = 0; k < 4; ++k) {
            int e = base + k * 512;
            bool v = (e < N_EDGES);
            dst[k] = v ? edges[N_EDGES + e] : 0;
            src[k] = v ? edges[e] : 0;
        }
        #pragma unroll
        for (int k = 0; k < 4; ++k) {
            int e = base + k * 512;
            if (e < N_EDGES)
                pos[k] = atomicAdd(&cursor[(size_t)dst[k] * CSTRIDE], 1);
        }
        #pragma unroll
        for (int k = 0; k < 4; ++k) {
            int e = base + k * 512;
            if (e < N_EDGES && pos[k] < MAXDEG)
                col[dst[k] * MAXDEG + pos[k]] = src[k];
        }
        return;
    }
    int m0 = b * 64;

    int ga = t >> 7, hq = (t >> 6) & 1, la = t & 63;
    int nodeA = m0 + ga * 16 + (la & 15);
    if (nodeA >= N_NODES) nodeA = N_NODES - 1;
    const float* Asrc = A + (size_t)nodeA * IN_CH + (la >> 4) * 8 + hq * 4;
    const uint4* Wg = (const uint4*)Wpk;
    int tb = t & ~63;                 // wave-uniform LDS slot base

    int w = t >> 6, lane = t & 63;
    int wm = w >> 2, wn = w & 3;
    int l15 = lane & 15, q = lane >> 4;

    f32x4 acc[4][2] = {};

    // prologue: stage chunk 0 -> buf0, chunk 1 -> buf1 (6 loads in flight)
    gload16(Wg + t,        &LDS[0][tb]);
    gload16(Wg + 512 + t,  &LDS[0][512 + tb]);
    gload16(Asrc,          &LDS[0][1024 + tb]);
    gload16(Wg + 1024 + t,       &LDS[1][tb]);
    gload16(Wg + 1024 + 512 + t, &LDS[1][512 + tb]);
    gload16(Asrc + 32,           &LDS[1][1024 + tb]);

    #define COMPUTE(bc)                                                           \
    {                                                                             \
        bf16x8 wf[4];                                                             \
        _Pragma("unroll")                                                         \
        for (int i = 0; i < 4; ++i)                                               \
            wf[i] = *(const bf16x8*)&LDS[bc][(wn * 4 + i) * 64 + lane];           \
        bf16x8 af[2];                                                             \
        _Pragma("unroll")                                                         \
        for (int g2 = 0; g2 < 2; ++g2) {                                          \
            f32x4 lo = *(const f32x4*)&LDS[bc][1024 + ((wm * 2 + g2) * 2 + 0) * 64 + lane]; \
            f32x4 hi = *(const f32x4*)&LDS[bc][1024 + ((wm * 2 + g2) * 2 + 1) * 64 + lane]; \
            uint4 pk;                                                             \
            pk.x = cvtpk(lo[0], lo[1]); pk.y = cvtpk(lo[2], lo[3]);               \
            pk.z = cvtpk(hi[0], hi[1]); pk.w = cvtpk(hi[2], hi[3]);               \
            af[g2] = __builtin_bit_cast(bf16x8, pk);                              \
        }                                                                         \
        _Pragma("unroll")                                                         \
        for (int i = 0; i < 4; ++i)                                               \
            _Pragma("unroll")                                                     \
            for (int g2 = 0; g2 < 2; ++g2)                                        \
                acc[i][g2] = __builtin_amdgcn_mfma_f32_16x16x32_bf16(wf[i], af[g2], acc[i][g2], 0, 0, 0); \
    }

    int bc = 0, bs = 2;               // compute buf, stage buf
    for (int c = 0; c < 30; ++c) {
        const uint4* ws = Wg + (size_t)(c + 2) * 1024;
        gload16(ws + t,       &LDS[bs][tb]);
        gload16(ws + 512 + t, &LDS[bs][512 + tb]);
        gload16(Asrc + (size_t)(c + 2) * 32, &LDS[bs][1024 + tb]);
        asm volatile("s_waitcnt vmcnt(6)" ::: "memory");
        __builtin_amdgcn_sched_barrier(0);
        __builtin_amdgcn_s_barrier();
        __builtin_amdgcn_sched_barrier(0);
        COMPUTE(bc);
        __builtin_amdgcn_s_barrier();
        __builtin_amdgcn_sched_barrier(0);
        bc = (bc == 2) ? 0 : bc + 1;
        bs = (bs == 2) ? 0 : bs + 1;
    }
    asm volatile("s_waitcnt vmcnt(3)" ::: "memory");
    __builtin_amdgcn_sched_barrier(0);
    __builtin_amdgcn_s_barrier();
    __builtin_amdgcn_sched_barrier(0);
    COMPUTE(bc);
    bc = (bc == 2) ? 0 : bc + 1;
    asm volatile("s_waitcnt vmcnt(0)" ::: "memory");
    __builtin_amdgcn_sched_barrier(0);
    __builtin_amdgcn_s_barrier();
    __builtin_amdgcn_sched_barrier(0);
    COMPUTE(bc);
    #undef COMPUTE

    #pragma unroll
    for (int g2 = 0; g2 < 2; ++g2) {
        int node = m0 + wm * 32 + g2 * 16 + l15;
        if (node < N_NODES) {
            ushort* base = (wn < 2) ? (Py + (size_t)node * FC + (wn & 1) * 64 + q * 4)
                                    : (Pz + (size_t)node * FC + (wn & 1) * 64 + q * 4);
            #pragma unroll
            for (int i = 0; i < 4; ++i) {
                f32x4 v = acc[i][g2];
                uint2 pk;
                pk.x = cvtpk(v[0], v[1]);
                pk.y = cvtpk(v[2], v[3]);
                *(uint2*)(base + i * 16) = pk;
            }
        }
    }
}

// ---------------- fused tail v3: 4-node CONCURRENT gather per wave ----------
// R12 lesson: tail is latency-bound (VALU 29%, HBM 7%, 550 GB/s random);
// serial 4-node loop lengthened the critical path. v3 keeps 32 nodes/block
// (W1s amortized) but interleaves the 4 nodes: per window, issue ALL active
// nodes' gather loads (<=16 uint4/lane in flight = 4x Little's law), then
// consume. Epilogue: Pz/addf loads batched; W1 k-loop fused across 4 nodes
// (1 W1s read -> 4 FMA; per-node serial depth /4).
__global__ __launch_bounds__(512, 4) void fused_tail(const ushort* __restrict__ Py,
                                                     const ushort* __restrict__ Pz,
                                                     const int* __restrict__ deg,
                                                     const int* __restrict__ col,
                                                     const float* __restrict__ addf,
                                                     const float* __restrict__ bl,
                                                     const float* __restrict__ W1,
                                                     const float* __restrict__ b1,
                                                     const float* __restrict__ W2,
                                                     const float* __restrict__ b2,
                                                     const float* __restrict__ gamma,
                                                     const float* __restrict__ beta,
                                                     const float* __restrict__ rmean,
                                                     const float* __restrict__ rvar,
                                                     float* __restrict__ out) {
    __shared__ float W1s[XCH][MID + 3];
    __shared__ float xbuf[32][XCH + 4];
    __shared__ float hbuf[32][MID + 3];
    int t = threadIdx.x;
    for (int idx = t; idx < MID * XCH; idx += 512) {
        int j = idx / XCH, k = idx - j * XCH;
        W1s[k][j] = W1[idx];
    }
    __syncthreads();
    int w = t >> 6, lane = t & 63;
    int g = lane >> 4, c16 = lane & 15;
    int nb = blockIdx.x * 32 + w * 4;     // this wave's 4 nodes

    int dd[4], cidx[4];
    #pragma unroll
    for (int k = 0; k < 4; ++k) {
        int n = nb + k;
        bool val = (n < N_NODES);
        int d = val ? deg[(size_t)n * CSTRIDE] : 0;
        if (d > MAXDEG) d = MAXDEG;
        dd[k] = d;
        cidx[k] = (val && d > 0) ? col[n * MAXDEG + (lane < d ? lane : 0)] : 0;
    }

    float s[4][8] = {};
    #pragma unroll 1
    for (int it = 0; it < 4; ++it) {
        int base = it * 16;
        if (!((base < dd[0]) | (base < dd[1]) | (base < dd[2]) | (base < dd[3]))) break;
        uint4 v[4][4];
        #pragma unroll
        for (int k = 0; k < 4; ++k) {
            if (base < dd[k]) {
                #pragma unroll
                for (int j = 0; j < 4; ++j) {
                    int ee = base + g + j * 4;
                    int e = __shfl(cidx[k], (ee < dd[k]) ? ee : 0);
                    v[k][j] = *(const uint4*)&Py[(size_t)e * FC + c16 * 8];
                }
            }
        }
        #pragma unroll
        for (int k = 0; k < 4; ++k) {
            if (base < dd[k]) {
                #pragma unroll
                for (int j = 0; j < 4; ++j) {
                    if (base + g + j * 4 < dd[k]) {
                        s[k][0] += bflo(v[k][j].x); s[k][1] += bfhi(v[k][j].x);
                        s[k][2] += bflo(v[k][j].y); s[k][3] += bfhi(v[k][j].y);
                        s[k][4] += bflo(v[k][j].z); s[k][5] += bfhi(v[k][j].z);
                        s[k][6] += bflo(v[k][j].w); s[k][7] += bfhi(v[k][j].w);
                    }
                }
            }
        }
    }
    #pragma unroll
    for (int k = 0; k < 4; ++k)
        #pragma unroll
        for (int r = 0; r < 8; ++r) {
            s[k][r] += __shfl_xor(s[k][r], 16);
            s[k][r] += __shfl_xor(s[k][r], 32);
        }

    // stash per-node sums (channels 0..127 laid out across lanes<16)
    #pragma unroll
    for (int k = 0; k < 4; ++k)
        if (lane < 16) {
            #pragma unroll
            for (int r = 0; r < 8; ++r) xbuf[w * 4 + k][lane * 8 + r] = s[k][r];
        }

    // batched epilogue loads (4 Pz + 4 addf in flight)
    unsigned vr[4]; float afv[4];
    #pragma unroll
    for (int k = 0; k < 4; ++k) {
        int n = nb + k;
        int nc = (n < N_NODES) ? n : N_NODES - 1;
        vr[k] = *(const unsigned*)&Pz[(size_t)nc * FC + lane * 2];
        afv[k] = (lane < ADD_CH) ? addf[(size_t)nc * ADD_CH + lane] : 0.f;
    }
    #pragma unroll
    for (int k = 0; k < 4; ++k) {
        int sidx = w * 4 + k;
        float invd = 1.0f / (float)(dd[k] > 1 ? dd[k] : 1);
        float x0 = xbuf[sidx][2 * lane] * invd + bl[2 * lane] + bflo(vr[k]);
        float x1 = xbuf[sidx][2 * lane + 1] * invd + bl[2 * lane + 1] + bfhi(vr[k]);
        x0 = (x0 >= 0.f) ? x0 : 0.01f * x0;
        x1 = (x1 >= 0.f) ? x1 : 0.01f * x1;
        xbuf[sidx][2 * lane] = x0;
        xbuf[sidx][2 * lane + 1] = x1;
        if (lane < ADD_CH) xbuf[sidx][FC + lane] = afv[k];
    }

    // MLP fused across the wave's 4 nodes: 1 W1s read -> 4 FMA
    if (lane < MID) {
        float h[4] = {b1[lane], b1[lane], b1[lane], b1[lane]};
        #pragma unroll 2
        for (int kk = 0; kk < XCH; ++kk) {
            float wv = W1s[kk][lane];
            h[0] += wv * xbuf[w * 4 + 0][kk];
            h[1] += wv * xbuf[w * 4 + 1][kk];
            h[2] += wv * xbuf[w * 4 + 2][kk];
            h[3] += wv * xbuf[w * 4 + 3][kk];
        }
        float ga_ = gamma[lane], bt = beta[lane], rm = rmean[lane];
        float rv = rsqrtf(rvar[lane] + 1e-5f);
        #pragma unroll
        for (int k = 0; k < 4; ++k) {
            float hh = fmaxf(h[k], 0.0f);
            hbuf[w * 4 + k][lane] = ga_ * (hh - rm) * rv + bt;
        }
    }
    if (lane < OUT_CH) {
        #pragma unroll
        for (int k = 0; k < 4; ++k) {
            int n = nb + k;
            if (n < N_NODES) {
                float o = b2[lane];
                #pragma unroll
                for (int j = 0; j < MID; ++j) o += W2[lane * MID + j] * hbuf[w * 4 + k][j];
                out[(size_t)n * OUT_CH + lane] = o;
            }
        }
    }
}

// ---------------- launch ----------------

extern "C" void kernel_launch(void* const* d_in, const int* in_sizes, int n_in,
                              void* d_out, int out_size, void* d_ws, size_t ws_size,
                              hipStream_t stream) {
    const float* features = (const float*)d_in[0];
    const int*   edges    = (const int*)d_in[1];
    const float* addf     = (const float*)d_in[4];
    const float* Wl       = (const float*)d_in[5];
    const float* bl       = (const float*)d_in[6];
    const float* Wr       = (const float*)d_in[7];
    const float* W1       = (const float*)d_in[8];
    const float* b1       = (const float*)d_in[9];
    const float* W2       = (const float*)d_in[10];
    const float* b2       = (const float*)d_in[11];
    const float* gamma    = (const float*)d_in[12];
    const float* beta     = (const float*)d_in[13];
    const float* rmean    = (const float*)d_in[14];
    const float* rvar     = (const float*)d_in[15];
    float* out = (float*)d_out;

    char* ws = (char*)d_ws;
    size_t off = 0;
    ushort* Py = (ushort*)(ws + off);     off += (size_t)N_NODES * FC * 2;            // 6.4 MB
    ushort* Pz = (ushort*)(ws + off);     off += (size_t)N_NODES * FC * 2;            // 6.4 MB
    ushort* Wpk = (ushort*)(ws + off);    off += (size_t)32 * 16 * 64 * 16;           // 512 KB
    int* cursor = (int*)(ws + off);       off += (size_t)N_NODES * CSTRIDE * 4;       // 1.6 MB
    int* col = (int*)(ws + off);          off += (size_t)N_NODES * MAXDEG * 4;        // 6.4 MB

    prep<<<WSWZ_B + ZERO_B, 512, 0, stream>>>(Wl, Wr, Wpk, cursor);

    gemm_build<<<GEMM_B + BUILD_B, 512, 0, stream>>>(features, Wpk, Py, Pz,
                                                     edges, cursor, col);

    fused_tail<<<(N_NODES + 31) / 32, 512, 0, stream>>>(Py, Pz, cursor, col, addf, bl,
                                                        W1, b1, W2, b2, gamma, beta,
                                                        rmean, rvar, out);
}